// Round 22
// baseline (335.351 us; speedup 1.0000x reference)
//
#include <hip/hip_runtime.h>

typedef short bf16x8 __attribute__((ext_vector_type(8)));
typedef float f32x4 __attribute__((ext_vector_type(4)));

#define DIM 128
#define NLAYER 3
#define NG 64
#define NC 10
#define NXCD 8
#define MAXDEG 64
#define NCHUNK 32
#define LROWE 136   // LDS row stride in ushorts (272 B -> 2-way alias, 16B-aligned)

static __device__ __forceinline__ float b2f(unsigned short u) {
  union { unsigned int i; float f; } x; x.i = ((unsigned int)u) << 16; return x.f;
}
static __device__ __forceinline__ unsigned short f2b(float f) {
  unsigned int x = __float_as_uint(f);
  unsigned int r = (x + 0x7FFFu + ((x >> 16) & 1u)) >> 16;
  return (unsigned short)r;
}

// ---- prep: zero hg + h0->bf16 + weight transpose ------------------------

__global__ __launch_bounds__(256) void k_prep(const float* __restrict__ h0,
    const float* __restrict__ wself, const float* __restrict__ wneigh,
    unsigned short* __restrict__ h_a, unsigned short* __restrict__ wtS,
    unsigned short* __restrict__ wtN, float* __restrict__ hg, int n) {
  int tid = blockIdx.x * 256 + threadIdx.x;
  int nthr = gridDim.x * 256;
  for (int i = tid; i < NG * DIM; i += nthr) hg[i] = 0.f;
  int tot4 = n * (DIM / 4);
  for (int i = tid; i < tot4; i += nthr) {
    float4 v = *(const float4*)(h0 + (size_t)i * 4);
    ushort4 r;
    r.x = f2b(v.x); r.y = f2b(v.y); r.z = f2b(v.z); r.w = f2b(v.w);
    *(ushort4*)(h_a + (size_t)i * 4) = r;
  }
  int totw = NLAYER * DIM * DIM;
  for (int i = tid; i < totw; i += nthr) {
    int l = i >> 14, rem = i & 16383, c = rem >> 7, k = rem & 127;
    int sidx = (l << 14) + (k << 7) + c;
    wtS[i] = f2b(wself[sidx]);
    wtN[i] = f2b(wneigh[sidx]);
  }
}

// ---- CSR-free padded adjacency via LDS counting sort --------------------
// Phase 1: block (bucket b, chunk c) histograms its edge chunk's in-bucket
// dsts in LDS (no global atomics), flushes to cnt[c][d].

__global__ __launch_bounds__(256) void k_cnt(const int* __restrict__ dst,
    int* __restrict__ cnt, int e, int n) {
  int bucket = blockIdx.x & (NXCD - 1), chunk = blockIdx.x >> 3;
  int bs = (n + NXCD - 1) / NXCD;
  int lo = bucket * bs, hi = min(n, lo + bs);
  __shared__ int lcnt[6272];
  for (int j = threadIdx.x; j < bs; j += 256) lcnt[j] = 0;
  __syncthreads();
  int ec = (e + NCHUNK - 1) / NCHUNK;
  int ebeg = chunk * ec, eend = min(e, ebeg + ec);
  for (int i = ebeg + threadIdx.x; i < eend; i += 256) {
    int d = __builtin_nontemporal_load(dst + i);
    if (d >= lo && d < hi) atomicAdd(&lcnt[d - lo], 1);
  }
  __syncthreads();
  for (int j = threadIdx.x; j < bs; j += 256) {
    int d = lo + j;
    if (d < n) cnt[chunk * n + d] = lcnt[j];
  }
}

// Phase 2: per-node exclusive scan over chunks (in place) + total degree.

__global__ __launch_bounds__(256) void k_scan(int* __restrict__ cnt,
    int* __restrict__ deg, int n) {
  int d = blockIdx.x * 256 + threadIdx.x;
  if (d >= n) return;
  int run = 0;
  #pragma unroll
  for (int c = 0; c < NCHUNK; ++c) {
    int t = cnt[c * n + d];
    cnt[c * n + d] = run;
    run += t;
  }
  deg[d] = run;
}

// Phase 3: LDS cursors from bases; slot assignment entirely in LDS.

__global__ __launch_bounds__(256) void k_fill(const int* __restrict__ src,
    const int* __restrict__ dst, const int* __restrict__ cnt,
    int* __restrict__ colxp, int e, int n) {
  int bucket = blockIdx.x & (NXCD - 1), chunk = blockIdx.x >> 3;
  int bs = (n + NXCD - 1) / NXCD;
  int lo = bucket * bs, hi = min(n, lo + bs);
  __shared__ int lcur[6272];
  for (int j = threadIdx.x; j < bs; j += 256) {
    int d = lo + j;
    lcur[j] = (d < n) ? cnt[chunk * n + d] : 0;
  }
  __syncthreads();
  int ec = (e + NCHUNK - 1) / NCHUNK;
  int ebeg = chunk * ec, eend = min(e, ebeg + ec);
  for (int i = ebeg + threadIdx.x; i < eend; i += 256) {
    int d = __builtin_nontemporal_load(dst + i);
    if (d >= lo && d < hi) {
      int p = atomicAdd(&lcur[d - lo], 1);
      if (p < MAXDEG) colxp[((size_t)d << 6) + p] = __builtin_nontemporal_load(src + i);
    }
  }
}

// ---- mean aggregation: one wave per node, 16 row-loads in flight --------

__global__ __launch_bounds__(256, 4) void k_agg(const unsigned short* __restrict__ h,
    const int* __restrict__ deg_, const int* __restrict__ colxp,
    unsigned short* __restrict__ agg, int n) {
  int wv = threadIdx.x >> 6, lane = threadIdx.x & 63;
  int v = blockIdx.x * 4 + wv;
  if (v >= n) return;
  int deg = deg_[v];
  int end = min(deg, MAXDEG);
  const int4* cp4 = (const int4*)(colxp + ((size_t)v << 6));
  int off = lane * 2;
  float a0[4], a1[4];
  #pragma unroll
  for (int k = 0; k < 4; ++k) { a0[k] = 0.f; a1[k] = 0.f; }
  for (int i = 0; i < end; i += 16) {
    int4 c0 = cp4[(i >> 2) + 0];
    int4 c1 = cp4[(i >> 2) + 1];
    int4 c2 = cp4[(i >> 2) + 2];
    int4 c3 = cp4[(i >> 2) + 3];
    int idxv[16] = {c0.x, c0.y, c0.z, c0.w, c1.x, c1.y, c1.z, c1.w,
                    c2.x, c2.y, c2.z, c2.w, c3.x, c3.y, c3.z, c3.w};
    unsigned int pk[16];
    #pragma unroll
    for (int k = 0; k < 16; ++k) {
      int s = (i + k < end) ? idxv[k] : 0;
      unsigned int p = *(const unsigned int*)(h + (size_t)s * DIM + off);
      pk[k] = (i + k < end) ? p : 0u;
    }
    #pragma unroll
    for (int k = 0; k < 16; ++k) {
      a0[k & 3] += __uint_as_float(pk[k] << 16);
      a1[k & 3] += __uint_as_float(pk[k] & 0xFFFF0000u);
    }
  }
  float s0 = (a0[0] + a0[1]) + (a0[2] + a0[3]);
  float s1 = (a1[0] + a1[1]) + (a1[2] + a1[3]);
  float w = 1.0f / fmaxf((float)deg, 1.0f);
  unsigned int outpk = (unsigned int)f2b(s0 * w) | ((unsigned int)f2b(s1 * w) << 16);
  *(unsigned int*)(agg + (size_t)v * DIM + off) = outpk;
}

// ---- dual-GEMM, weight-stationary + coalesced LDS staging ---------------

__global__ __launch_bounds__(512, 2) void k_gemm(const unsigned short* __restrict__ hin,
    const unsigned short* __restrict__ agg, const unsigned short* __restrict__ wtS,
    const unsigned short* __restrict__ wtN, const float* __restrict__ bias,
    unsigned short* __restrict__ hout, int n) {
  __shared__ unsigned short ldsA[16 * LROWE];
  __shared__ unsigned short ldsG[16 * LROWE];
  int lane = threadIdx.x & 63, wv = threadIdx.x >> 6;
  int r = lane & 15, q = lane >> 4;
  int cf = wv;
  const unsigned short* wsp = wtS + (size_t)(cf * 16 + r) * DIM + q * 8;
  const unsigned short* wnp = wtN + (size_t)(cf * 16 + r) * DIM + q * 8;
  bf16x8 ws[4], wn[4];
  #pragma unroll
  for (int kf = 0; kf < 4; ++kf) {
    ws[kf] = *(const bf16x8*)(wsp + kf * 32);
    wn[kf] = *(const bf16x8*)(wnp + kf * 32);
  }
  int col = cf * 16 + r;
  float bval = bias[col];
  int ntiles = (n + 15) >> 4;
  int st = threadIdx.x & 255;
  int srow = st >> 4, schunk = st & 15;
  bool doG = threadIdx.x >= 256;
  for (int tb = blockIdx.x; tb < ntiles; tb += gridDim.x) {
    int row0 = tb * 16;
    {
      int grow = row0 + srow; if (grow > n - 1) grow = n - 1;
      const unsigned short* sp = (doG ? agg : hin) + (size_t)grow * DIM + schunk * 8;
      unsigned short* dp = (doG ? ldsG : ldsA) + srow * LROWE + schunk * 8;
      *(int4*)dp = *(const int4*)sp;
    }
    __syncthreads();
    bf16x8 ah[4], ag[4];
    #pragma unroll
    for (int kf = 0; kf < 4; ++kf) {
      ah[kf] = *(const bf16x8*)(ldsA + r * LROWE + q * 8 + kf * 32);
      ag[kf] = *(const bf16x8*)(ldsG + r * LROWE + q * 8 + kf * 32);
    }
    f32x4 acc = {0.f, 0.f, 0.f, 0.f};
    #pragma unroll
    for (int kf = 0; kf < 4; ++kf)
      acc = __builtin_amdgcn_mfma_f32_16x16x32_bf16(ah[kf], ws[kf], acc, 0, 0, 0);
    #pragma unroll
    for (int kf = 0; kf < 4; ++kf)
      acc = __builtin_amdgcn_mfma_f32_16x16x32_bf16(ag[kf], wn[kf], acc, 0, 0, 0);
    #pragma unroll
    for (int j = 0; j < 4; ++j) {
      int orow = row0 + q * 4 + j;
      if (orow < n) {
        float vv = acc[j] + bval;
        vv = vv > 0.f ? vv : 0.f;
        hout[(size_t)orow * DIM + col] = f2b(vv);
      }
    }
    __syncthreads();
  }
}

// ---- readout: sorted graph_id -> run-length register accumulation -------

__global__ __launch_bounds__(256) void k_readout(const unsigned short* __restrict__ h,
    const int* __restrict__ gid, float* __restrict__ hg, int n) {
  int c = threadIdx.x & 127, half = threadIdx.x >> 7;
  int per = (n + gridDim.x - 1) / gridDim.x;
  int beg = blockIdx.x * per;
  int end = beg + per; if (end > n) end = n;
  int curg = -1;
  float acc = 0.f;
  for (int v = beg + half; v < end; v += 2) {
    int g = gid[v];
    if (g != curg) {
      if (curg >= 0) atomicAdd(&hg[curg * DIM + c], acc);
      curg = g; acc = 0.f;
    }
    acc += b2f(h[(size_t)v * DIM + c]);
  }
  if (curg >= 0) atomicAdd(&hg[curg * DIM + c], acc);
}

// ---- head: counts via binary search on sorted gid, then [G,D]@[D,C] -----

__global__ void k_head(const float* __restrict__ hg, const int* __restrict__ gid, int n,
    const float* __restrict__ wcls, const float* __restrict__ bcls,
    float* __restrict__ out) {
  __shared__ float sinv[NG];
  int t = threadIdx.x;
  if (t < NG) {
    int lo = 0, hi = n;
    while (lo < hi) { int mid = (lo + hi) >> 1; if (gid[mid] < t) lo = mid + 1; else hi = mid; }
    int lo2 = lo, hi2 = n;
    while (lo2 < hi2) { int mid = (lo2 + hi2) >> 1; if (gid[mid] < t + 1) lo2 = mid + 1; else hi2 = mid; }
    int cntg = lo2 - lo;
    sinv[t] = 1.0f / fmaxf((float)cntg, 1.0f);
  }
  __syncthreads();
  if (t >= NG * NC) return;
  int g = t / NC, c = t % NC;
  float s = 0.f;
  for (int k = 0; k < DIM; ++k) s += hg[g * DIM + k] * wcls[k * NC + c];
  out[t] = s * sinv[g] + bcls[c];
}

// ---- launch -------------------------------------------------------------

extern "C" void kernel_launch(void* const* d_in, const int* in_sizes, int n_in,
                              void* d_out, int out_size, void* d_ws, size_t ws_size,
                              hipStream_t stream) {
  const float* h0   = (const float*)d_in[0];
  const int* src    = (const int*)d_in[1];
  const int* dst    = (const int*)d_in[2];
  const int* gid    = (const int*)d_in[3];
  const float* wself  = (const float*)d_in[5];
  const float* wneigh = (const float*)d_in[6];
  const float* bias   = (const float*)d_in[7];
  const float* wcls   = (const float*)d_in[8];
  const float* bcls   = (const float*)d_in[9];
  int n = in_sizes[0] / DIM;
  int e = in_sizes[1];
  (void)n_in; (void)out_size; (void)ws_size;

  char* ws = (char*)d_ws;
  size_t o = 0;
  auto alloc = [&](size_t bytes) {
    char* p = ws + o;
    o = (o + bytes + 255) & ~(size_t)255;
    return p;
  };
  unsigned short* h_a   = (unsigned short*)alloc((size_t)n * DIM * 2);
  unsigned short* h_b   = (unsigned short*)alloc((size_t)n * DIM * 2);
  unsigned short* aggb  = (unsigned short*)alloc((size_t)n * DIM * 2);
  unsigned short* wtS   = (unsigned short*)alloc((size_t)NLAYER * DIM * DIM * 2);
  unsigned short* wtN   = (unsigned short*)alloc((size_t)NLAYER * DIM * DIM * 2);
  int*   deg   = (int*)alloc((size_t)n * 4);
  int*   cnt   = (int*)alloc((size_t)NCHUNK * n * 4);
  int*   colxp = (int*)alloc((size_t)n * MAXDEG * 4);
  float* hg    = (float*)alloc((size_t)NG * DIM * 4);

  k_prep<<<2048, 256, 0, stream>>>(h0, wself, wneigh, h_a, wtS, wtN, hg, n);
  k_cnt<<<NXCD * NCHUNK, 256, 0, stream>>>(dst, cnt, e, n);
  k_scan<<<(n + 255) / 256, 256, 0, stream>>>(cnt, deg, n);
  k_fill<<<NXCD * NCHUNK, 256, 0, stream>>>(src, dst, cnt, colxp, e, n);

  const unsigned short* hin = h_a;
  unsigned short* hout = h_b;
  for (int l = 0; l < NLAYER; ++l) {
    k_agg<<<(n + 3) / 4, 256, 0, stream>>>(hin, deg, colxp, aggb, n);
    k_gemm<<<1024, 512, 0, stream>>>(hin, aggb, wtS + l * DIM * DIM,
                                     wtN + l * DIM * DIM, bias + l * DIM,
                                     hout, n);
    const unsigned short* t = hin;
    hin = hout;
    hout = (unsigned short*)t;
  }
  k_readout<<<512, 256, 0, stream>>>(hin, gid, hg, n);
  k_head<<<1, 640, 0, stream>>>(hg, gid, n, wcls, bcls, (float*)d_out);
}

// Round 23
// 222.553 us; speedup vs baseline: 1.5068x; 1.5068x over previous
//
#include <hip/hip_runtime.h>

typedef short bf16x8 __attribute__((ext_vector_type(8)));
typedef float f32x4 __attribute__((ext_vector_type(4)));

#define DIM 128
#define NLAYER 3
#define NG 64
#define NC 10
#define NXCD 8
#define MAXDEG 64
#define LROWE 136   // LDS row stride in ushorts (272 B -> 2-way alias, 16B-aligned)

static __device__ __forceinline__ float b2f(unsigned short u) {
  union { unsigned int i; float f; } x; x.i = ((unsigned int)u) << 16; return x.f;
}
static __device__ __forceinline__ unsigned short f2b(float f) {
  unsigned int x = __float_as_uint(f);
  unsigned int r = (x + 0x7FFFu + ((x >> 16) & 1u)) >> 16;
  return (unsigned short)r;
}

// ---- prep: zero cur + zero hg + h0->bf16 + weight transpose -------------

__global__ __launch_bounds__(256) void k_prep(const float* __restrict__ h0,
    const float* __restrict__ wself, const float* __restrict__ wneigh,
    unsigned short* __restrict__ h_a, unsigned short* __restrict__ wtS,
    unsigned short* __restrict__ wtN, int* __restrict__ cur,
    float* __restrict__ hg, int n) {
  int tid = blockIdx.x * 256 + threadIdx.x;
  int nthr = gridDim.x * 256;
  for (int i = tid; i < n; i += nthr) cur[i] = 0;
  for (int i = tid; i < NG * DIM; i += nthr) hg[i] = 0.f;
  int tot4 = n * (DIM / 4);
  for (int i = tid; i < tot4; i += nthr) {
    float4 v = *(const float4*)(h0 + (size_t)i * 4);
    ushort4 r;
    r.x = f2b(v.x); r.y = f2b(v.y); r.z = f2b(v.z); r.w = f2b(v.w);
    *(ushort4*)(h_a + (size_t)i * 4) = r;
  }
  int totw = NLAYER * DIM * DIM;
  for (int i = tid; i < totw; i += nthr) {
    int l = i >> 14, rem = i & 16383, c = rem >> 7, k = rem & 127;
    int sidx = (l << 14) + (k << 7) + c;
    wtS[i] = f2b(wself[sidx]);
    wtN[i] = f2b(wneigh[sidx]);
  }
}

// ---- padded adjacency fill, XCD-bucketed, nt streaming loads ------------
// 42 us = L2 atomic-throughput floor (1 atomic/cycle/XCD); proven
// insensitive to occupancy (R11) and not beatable by LDS sort (R22).

__global__ __launch_bounds__(256) void k_fillp(const int* __restrict__ src,
    const int* __restrict__ dst, int* __restrict__ cur, int* __restrict__ colxp,
    int e, int n) {
  int bucket = blockIdx.x & (NXCD - 1);
  int chunk = blockIdx.x >> 3, nchunk = gridDim.x >> 3;
  int bs = (n + NXCD - 1) / NXCD;
  int lo = bucket * bs, hi = min(n, lo + bs);
  for (int i = chunk * 256 + threadIdx.x; i < e; i += nchunk * 256) {
    int d = __builtin_nontemporal_load(dst + i);
    if (d >= lo && d < hi) {
      int p = atomicAdd(&cur[d], 1);
      if (p < MAXDEG) colxp[(size_t)d * MAXDEG + p] = __builtin_nontemporal_load(src + i);
    }
  }
}

// ---- mean aggregation: one wave per node, 16 row-loads in flight --------

__global__ __launch_bounds__(256, 4) void k_agg(const unsigned short* __restrict__ h,
    const int* __restrict__ cur, const int* __restrict__ colxp,
    unsigned short* __restrict__ agg, int n) {
  int wv = threadIdx.x >> 6, lane = threadIdx.x & 63;
  int v = blockIdx.x * 4 + wv;
  if (v >= n) return;
  int deg = cur[v];
  int end = min(deg, MAXDEG);
  const int4* cp4 = (const int4*)(colxp + (size_t)v * MAXDEG);
  int off = lane * 2;
  float a0[4], a1[4];
  #pragma unroll
  for (int k = 0; k < 4; ++k) { a0[k] = 0.f; a1[k] = 0.f; }
  for (int i = 0; i < end; i += 16) {
    int4 c0 = cp4[(i >> 2) + 0];
    int4 c1 = cp4[(i >> 2) + 1];
    int4 c2 = cp4[(i >> 2) + 2];
    int4 c3 = cp4[(i >> 2) + 3];
    int idxv[16] = {c0.x, c0.y, c0.z, c0.w, c1.x, c1.y, c1.z, c1.w,
                    c2.x, c2.y, c2.z, c2.w, c3.x, c3.y, c3.z, c3.w};
    unsigned int pk[16];
    #pragma unroll
    for (int k = 0; k < 16; ++k) {
      int s = (i + k < end) ? idxv[k] : 0;
      unsigned int p = *(const unsigned int*)(h + (size_t)s * DIM + off);
      pk[k] = (i + k < end) ? p : 0u;
    }
    #pragma unroll
    for (int k = 0; k < 16; ++k) {
      a0[k & 3] += __uint_as_float(pk[k] << 16);
      a1[k & 3] += __uint_as_float(pk[k] & 0xFFFF0000u);
    }
  }
  float s0 = (a0[0] + a0[1]) + (a0[2] + a0[3]);
  float s1 = (a1[0] + a1[1]) + (a1[2] + a1[3]);
  float w = 1.0f / fmaxf((float)deg, 1.0f);
  unsigned int outpk = (unsigned int)f2b(s0 * w) | ((unsigned int)f2b(s1 * w) << 16);
  *(unsigned int*)(agg + (size_t)v * DIM + off) = outpk;
}

// ---- dual-GEMM, weight-stationary + coalesced LDS staging ---------------

__global__ __launch_bounds__(512, 2) void k_gemm(const unsigned short* __restrict__ hin,
    const unsigned short* __restrict__ agg, const unsigned short* __restrict__ wtS,
    const unsigned short* __restrict__ wtN, const float* __restrict__ bias,
    unsigned short* __restrict__ hout, int n) {
  __shared__ unsigned short ldsA[16 * LROWE];
  __shared__ unsigned short ldsG[16 * LROWE];
  int lane = threadIdx.x & 63, wv = threadIdx.x >> 6;
  int r = lane & 15, q = lane >> 4;
  int cf = wv;
  const unsigned short* wsp = wtS + (size_t)(cf * 16 + r) * DIM + q * 8;
  const unsigned short* wnp = wtN + (size_t)(cf * 16 + r) * DIM + q * 8;
  bf16x8 ws[4], wn[4];
  #pragma unroll
  for (int kf = 0; kf < 4; ++kf) {
    ws[kf] = *(const bf16x8*)(wsp + kf * 32);
    wn[kf] = *(const bf16x8*)(wnp + kf * 32);
  }
  int col = cf * 16 + r;
  float bval = bias[col];
  int ntiles = (n + 15) >> 4;
  int st = threadIdx.x & 255;
  int srow = st >> 4, schunk = st & 15;
  bool doG = threadIdx.x >= 256;
  for (int tb = blockIdx.x; tb < ntiles; tb += gridDim.x) {
    int row0 = tb * 16;
    {
      int grow = row0 + srow; if (grow > n - 1) grow = n - 1;
      const unsigned short* sp = (doG ? agg : hin) + (size_t)grow * DIM + schunk * 8;
      unsigned short* dp = (doG ? ldsG : ldsA) + srow * LROWE + schunk * 8;
      *(int4*)dp = *(const int4*)sp;
    }
    __syncthreads();
    bf16x8 ah[4], ag[4];
    #pragma unroll
    for (int kf = 0; kf < 4; ++kf) {
      ah[kf] = *(const bf16x8*)(ldsA + r * LROWE + q * 8 + kf * 32);
      ag[kf] = *(const bf16x8*)(ldsG + r * LROWE + q * 8 + kf * 32);
    }
    f32x4 acc = {0.f, 0.f, 0.f, 0.f};
    #pragma unroll
    for (int kf = 0; kf < 4; ++kf)
      acc = __builtin_amdgcn_mfma_f32_16x16x32_bf16(ah[kf], ws[kf], acc, 0, 0, 0);
    #pragma unroll
    for (int kf = 0; kf < 4; ++kf)
      acc = __builtin_amdgcn_mfma_f32_16x16x32_bf16(ag[kf], wn[kf], acc, 0, 0, 0);
    #pragma unroll
    for (int j = 0; j < 4; ++j) {
      int orow = row0 + q * 4 + j;
      if (orow < n) {
        float vv = acc[j] + bval;
        vv = vv > 0.f ? vv : 0.f;
        hout[(size_t)orow * DIM + col] = f2b(vv);
      }
    }
    __syncthreads();
  }
}

// ---- readout: sorted graph_id -> run-length register accumulation -------

__global__ __launch_bounds__(256) void k_readout(const unsigned short* __restrict__ h,
    const int* __restrict__ gid, float* __restrict__ hg, int n) {
  int c = threadIdx.x & 127, half = threadIdx.x >> 7;
  int per = (n + gridDim.x - 1) / gridDim.x;
  int beg = blockIdx.x * per;
  int end = beg + per; if (end > n) end = n;
  int curg = -1;
  float acc = 0.f;
  for (int v = beg + half; v < end; v += 2) {
    int g = gid[v];
    if (g != curg) {
      if (curg >= 0) atomicAdd(&hg[curg * DIM + c], acc);
      curg = g; acc = 0.f;
    }
    acc += b2f(h[(size_t)v * DIM + c]);
  }
  if (curg >= 0) atomicAdd(&hg[curg * DIM + c], acc);
}

// ---- head: counts via binary search on sorted gid, then [G,D]@[D,C] -----

__global__ void k_head(const float* __restrict__ hg, const int* __restrict__ gid, int n,
    const float* __restrict__ wcls, const float* __restrict__ bcls,
    float* __restrict__ out) {
  __shared__ float sinv[NG];
  int t = threadIdx.x;
  if (t < NG) {
    int lo = 0, hi = n;
    while (lo < hi) { int mid = (lo + hi) >> 1; if (gid[mid] < t) lo = mid + 1; else hi = mid; }
    int lo2 = lo, hi2 = n;
    while (lo2 < hi2) { int mid = (lo2 + hi2) >> 1; if (gid[mid] < t + 1) lo2 = mid + 1; else hi2 = mid; }
    int cntg = lo2 - lo;
    sinv[t] = 1.0f / fmaxf((float)cntg, 1.0f);
  }
  __syncthreads();
  if (t >= NG * NC) return;
  int g = t / NC, c = t % NC;
  float s = 0.f;
  for (int k = 0; k < DIM; ++k) s += hg[g * DIM + k] * wcls[k * NC + c];
  out[t] = s * sinv[g] + bcls[c];
}

// ---- launch -------------------------------------------------------------

extern "C" void kernel_launch(void* const* d_in, const int* in_sizes, int n_in,
                              void* d_out, int out_size, void* d_ws, size_t ws_size,
                              hipStream_t stream) {
  const float* h0   = (const float*)d_in[0];
  const int* src    = (const int*)d_in[1];
  const int* dst    = (const int*)d_in[2];
  const int* gid    = (const int*)d_in[3];
  const float* wself  = (const float*)d_in[5];
  const float* wneigh = (const float*)d_in[6];
  const float* bias   = (const float*)d_in[7];
  const float* wcls   = (const float*)d_in[8];
  const float* bcls   = (const float*)d_in[9];
  int n = in_sizes[0] / DIM;
  int e = in_sizes[1];
  (void)n_in; (void)out_size; (void)ws_size;

  char* ws = (char*)d_ws;
  size_t o = 0;
  auto alloc = [&](size_t bytes) {
    char* p = ws + o;
    o = (o + bytes + 255) & ~(size_t)255;
    return p;
  };
  unsigned short* h_a   = (unsigned short*)alloc((size_t)n * DIM * 2);
  unsigned short* h_b   = (unsigned short*)alloc((size_t)n * DIM * 2);
  unsigned short* aggb  = (unsigned short*)alloc((size_t)n * DIM * 2);
  unsigned short* wtS   = (unsigned short*)alloc((size_t)NLAYER * DIM * DIM * 2);
  unsigned short* wtN   = (unsigned short*)alloc((size_t)NLAYER * DIM * DIM * 2);
  int*   cur   = (int*)alloc((size_t)n * 4);
  int*   colxp = (int*)alloc((size_t)n * MAXDEG * 4);
  float* hg    = (float*)alloc((size_t)NG * DIM * 4);

  k_prep<<<2048, 256, 0, stream>>>(h0, wself, wneigh, h_a, wtS, wtN, cur, hg, n);
  k_fillp<<<2048, 256, 0, stream>>>(src, dst, cur, colxp, e, n);

  const unsigned short* hin = h_a;
  unsigned short* hout = h_b;
  for (int l = 0; l < NLAYER; ++l) {
    k_agg<<<(n + 3) / 4, 256, 0, stream>>>(hin, cur, colxp, aggb, n);
    k_gemm<<<1024, 512, 0, stream>>>(hin, aggb, wtS + l * DIM * DIM,
                                     wtN + l * DIM * DIM, bias + l * DIM,
                                     hout, n);
    const unsigned short* t = hin;
    hin = hout;
    hout = (unsigned short*)t;
  }
  k_readout<<<512, 256, 0, stream>>>(hin, gid, hg, n);
  k_head<<<1, 640, 0, stream>>>(hg, gid, n, wcls, bcls, (float*)d_out);
}